// Round 1
// baseline (3125.996 us; speedup 1.0000x reference)
//
#include <hip/hip_runtime.h>
#include <math.h>

#define BATCH 65536
#define FDIM 16
#define CDIM 128
#define HDIM 256
#define NL 8
#define KBINS 8
#define TDIM 8
#define PD 23      // 3*K-1
#define TBV 3.0f

// GEMM tiling
#define BR 64
#define BC 64
#define KT 16

__global__ __launch_bounds__(256)
void prep_kernel(const float* __restrict__ in, float* __restrict__ x,
                 float* __restrict__ ldet, int rows) {
    int idx = blockIdx.x * 256 + threadIdx.x;
    int total = rows * FDIM;
    if (idx < total) {
        float v = in[idx];
        x[idx] = fminf(fmaxf(v, -1.f), 1.f);
    }
    if (idx < rows) ldet[idx] = 0.f;
}

// C = [relu](A @ W + b); A either plain rows x K, or concat([x[:,idn], ctx])
template<int CONCAT, int RELU>
__global__ __launch_bounds__(256)
void gemm_kernel(const float* __restrict__ A,
                 const float* __restrict__ xbuf,
                 const float* __restrict__ ctx,
                 const float* __restrict__ W,
                 const float* __restrict__ bias,
                 float* __restrict__ out,
                 int K, int N, int xoff) {
    __shared__ float As[KT][BR];   // transposed: As[k][r]
    __shared__ float Ws[KT][BC];
    int tid = threadIdx.x;
    int r0 = blockIdx.x * BR;
    int c0 = blockIdx.y * BC;
    int ty = tid >> 4, tx = tid & 15;
    float acc[4][4] = {};
    int ktiles = (K + KT - 1) / KT;
    for (int kt = 0; kt < ktiles; ++kt) {
        int k0 = kt * KT;
        // load A tile
        #pragma unroll
        for (int j = 0; j < 4; ++j) {
            int idx = tid + j * 256;
            int k = idx & (KT - 1);
            int rr = idx >> 4;
            int gk = k0 + k;
            float v = 0.f;
            if (gk < K) {
                if (CONCAT) {
                    int gr = r0 + rr;
                    v = (gk < TDIM) ? xbuf[gr * FDIM + 2 * gk + xoff]
                                    : ctx[(size_t)gr * CDIM + (gk - TDIM)];
                } else {
                    v = A[(size_t)(r0 + rr) * K + gk];
                }
            }
            As[k][rr] = v;
        }
        // load W tile
        #pragma unroll
        for (int j = 0; j < 4; ++j) {
            int idx = tid + j * 256;
            int c = idx & (BC - 1);
            int kk = idx >> 6;
            int gk = k0 + kk, gc = c0 + c;
            Ws[kk][c] = (gk < K && gc < N) ? W[(size_t)gk * N + gc] : 0.f;
        }
        __syncthreads();
        #pragma unroll
        for (int k = 0; k < KT; ++k) {
            float4 a4 = *(const float4*)&As[k][ty * 4];
            float4 w4 = *(const float4*)&Ws[k][tx * 4];
            float av[4] = {a4.x, a4.y, a4.z, a4.w};
            float wv[4] = {w4.x, w4.y, w4.z, w4.w};
            #pragma unroll
            for (int ii = 0; ii < 4; ++ii)
                #pragma unroll
                for (int jj = 0; jj < 4; ++jj)
                    acc[ii][jj] = fmaf(av[ii], wv[jj], acc[ii][jj]);
        }
        __syncthreads();
    }
    #pragma unroll
    for (int ii = 0; ii < 4; ++ii) {
        int r = r0 + ty * 4 + ii;
        int c = c0 + tx * 4;
        if (c < N) {
            float4 b4 = *(const float4*)&bias[c];
            float o0 = acc[ii][0] + b4.x;
            float o1 = acc[ii][1] + b4.y;
            float o2 = acc[ii][2] + b4.z;
            float o3 = acc[ii][3] + b4.w;
            if (RELU) {
                o0 = fmaxf(o0, 0.f); o1 = fmaxf(o1, 0.f);
                o2 = fmaxf(o2, 0.f); o3 = fmaxf(o3, 0.f);
            }
            float4 o = {o0, o1, o2, o3};
            *(float4*)&out[(size_t)r * N + c] = o;
        }
    }
}

__device__ __forceinline__ float softplusf(float v) {
    return fmaxf(v, 0.f) + log1pf(expf(-fabsf(v)));
}

// Fused: RQ spline + un-split (inv) + inter-layer permutation + logdet reduce.
// For layer NL-1: writes clipped x and final logdet to out_final.
__global__ __launch_bounds__(256)
void spline_kernel(const float* __restrict__ x_old, const float* __restrict__ p,
                   const int* __restrict__ perms,
                   float* __restrict__ x_new, float* __restrict__ ldet,
                   float* __restrict__ out_final,
                   int layer, int row_base) {
    int tid = threadIdx.x;
    int f = tid & 15;
    int r = blockIdx.x * 16 + (tid >> 4);
    int g = (layer < NL - 1) ? perms[layer * FDIM + f] : f;
    float val;
    float ld = 0.f;
    if ((g & 1) == (layer & 1)) {   // transformed feature
        int t = g >> 1;
        float xin = x_old[(size_t)r * FDIM + g];
        const float* pp = &p[((size_t)r * TDIM + t) * PD];
        float uw[KBINS], uh[KBINS], ud[KBINS - 1];
        #pragma unroll
        for (int k = 0; k < KBINS; ++k) uw[k] = pp[k];
        #pragma unroll
        for (int k = 0; k < KBINS; ++k) uh[k] = pp[KBINS + k];
        #pragma unroll
        for (int k = 0; k < KBINS - 1; ++k) ud[k] = pp[2 * KBINS + k];

        // softmax widths
        float mw = uw[0];
        #pragma unroll
        for (int k = 1; k < KBINS; ++k) mw = fmaxf(mw, uw[k]);
        float ew[KBINS], sw = 0.f;
        #pragma unroll
        for (int k = 0; k < KBINS; ++k) { ew[k] = expf(uw[k] - mw); sw += ew[k]; }
        float cw[KBINS + 1];
        cw[0] = -TBV;
        {
            float s = 0.f;
            float inv = 1.f / sw;
            #pragma unroll
            for (int k = 0; k < KBINS; ++k) {
                float wk = 0.001f + (1.f - 0.001f * KBINS) * ew[k] * inv;
                s += wk;
                cw[k + 1] = 2.f * TBV * s - TBV;
            }
            cw[KBINS] = TBV;
        }
        // softmax heights
        float mh = uh[0];
        #pragma unroll
        for (int k = 1; k < KBINS; ++k) mh = fmaxf(mh, uh[k]);
        float eh[KBINS], sh = 0.f;
        #pragma unroll
        for (int k = 0; k < KBINS; ++k) { eh[k] = expf(uh[k] - mh); sh += eh[k]; }
        float ch[KBINS + 1];
        ch[0] = -TBV;
        {
            float s = 0.f;
            float inv = 1.f / sh;
            #pragma unroll
            for (int k = 0; k < KBINS; ++k) {
                float hk = 0.001f + (1.f - 0.001f * KBINS) * eh[k] * inv;
                s += hk;
                ch[k + 1] = 2.f * TBV * s - TBV;
            }
            ch[KBINS] = TBV;
        }
        // derivatives (boundary = 1.0)
        float d[KBINS + 1];
        d[0] = 1.f; d[KBINS] = 1.f;
        #pragma unroll
        for (int k = 1; k < KBINS; ++k) d[k] = 0.001f + softplusf(ud[k - 1]);

        bool inside = (xin >= -TBV) && (xin <= TBV);
        float xs = fminf(fmaxf(xin, -TBV), TBV);
        int idx = 0;
        #pragma unroll
        for (int k = 1; k < KBINS; ++k) idx += (xs >= cw[k]) ? 1 : 0;
        float x0 = cw[0], x1 = cw[1], y0 = ch[0], y1 = ch[1], d0 = d[0], d1 = d[1];
        #pragma unroll
        for (int k = 0; k < KBINS; ++k) {
            if (idx == k) { x0 = cw[k]; x1 = cw[k + 1]; y0 = ch[k]; y1 = ch[k + 1]; d0 = d[k]; d1 = d[k + 1]; }
        }
        float bw = x1 - x0, bh = y1 - y0;
        float delta = bh / bw;
        float th = (xs - x0) / bw;
        float th1m = th * (1.f - th);
        float num = bh * (delta * th * th + d0 * th1m);
        float den = delta + (d0 + d1 - 2.f * delta) * th1m;
        float y = y0 + num / den;
        float omth = 1.f - th;
        float dnum = delta * delta * (d1 * th * th + 2.f * delta * th1m + d0 * omth * omth);
        float ldv = logf(dnum) - 2.f * logf(den);
        val = inside ? y : xin;
        ld = inside ? ldv : 0.f;
    } else {
        val = x_old[(size_t)r * FDIM + g];
    }
    // reduce ld across the 16-lane row group (deterministic)
    #pragma unroll
    for (int o = 1; o < 16; o <<= 1) ld += __shfl_xor(ld, o, 64);

    if (layer == NL - 1) {
        int gr = row_base + r;
        out_final[(size_t)gr * FDIM + f] = fminf(fmaxf(val, -1.f), 1.f);
        if (f == 0) out_final[(size_t)BATCH * FDIM + gr] = ldet[r] + ld;
    } else {
        x_new[(size_t)r * FDIM + f] = val;
        if (f == 0) ldet[r] += ld;
    }
}

extern "C" void kernel_launch(void* const* d_in, const int* in_sizes, int n_in,
                              void* d_out, int out_size, void* d_ws, size_t ws_size,
                              hipStream_t stream) {
    (void)in_sizes; (void)n_in; (void)out_size;
    const float* inputs  = (const float*)d_in[0];
    const float* context = (const float*)d_in[1];
    const float* W1 = (const float*)d_in[2];
    const float* b1 = (const float*)d_in[3];
    const float* W2 = (const float*)d_in[4];
    const float* b2 = (const float*)d_in[5];
    const float* W3 = (const float*)d_in[6];
    const float* b3 = (const float*)d_in[7];
    const int*   perms = (const int*)d_in[8];
    float* out = (float*)d_out;

    // per-row ws floats: x_a(16) + x_b(16) + ldet(1) + h1(256, also p) + h2(256)
    const size_t per_row_bytes = (size_t)(16 + 16 + 1 + 256 + 256) * 4;
    int rows = BATCH;
    while ((size_t)rows * per_row_bytes > ws_size && rows > 64) rows >>= 1;

    for (int base = 0; base < BATCH; base += rows) {
        float* x_a  = (float*)d_ws;
        float* x_b  = x_a + (size_t)rows * 16;
        float* ldet = x_b + (size_t)rows * 16;
        float* h1   = ldet + rows;                 // also holds p
        float* h2   = h1 + (size_t)rows * 256;

        prep_kernel<<<(rows * 16 + 255) / 256, 256, 0, stream>>>(
            inputs + (size_t)base * 16, x_a, ldet, rows);

        float* xo = x_a;
        float* xn = x_b;
        for (int l = 0; l < NL; ++l) {
            int xoff = 1 - (l & 1);   // idn[k] = 2k + xoff
            gemm_kernel<1, 1><<<dim3(rows / BR, HDIM / BC), 256, 0, stream>>>(
                nullptr, xo, context + (size_t)base * CDIM,
                W1 + (size_t)l * (TDIM + CDIM) * HDIM, b1 + (size_t)l * HDIM,
                h1, TDIM + CDIM, HDIM, xoff);
            gemm_kernel<0, 1><<<dim3(rows / BR, HDIM / BC), 256, 0, stream>>>(
                h1, nullptr, nullptr,
                W2 + (size_t)l * HDIM * HDIM, b2 + (size_t)l * HDIM,
                h2, HDIM, HDIM, 0);
            gemm_kernel<0, 0><<<dim3(rows / BR, (TDIM * PD + BC - 1) / BC), 256, 0, stream>>>(
                h2, nullptr, nullptr,
                W3 + (size_t)l * HDIM * (TDIM * PD), b3 + (size_t)l * (TDIM * PD),
                h1 /* p */, HDIM, TDIM * PD, 0);
            spline_kernel<<<rows / 16, 256, 0, stream>>>(
                xo, h1, perms, xn, ldet, out, l, base);
            float* tmp = xo; xo = xn; xn = tmp;
        }
    }
}

// Round 3
// 1273.810 us; speedup vs baseline: 2.4541x; 2.4541x over previous
//
#include <hip/hip_runtime.h>
#include <math.h>

#define BATCH 65536
#define FDIM 16
#define CDIM 128
#define HDIM 256
#define NL 8
#define KBINS 8
#define TDIM 8
#define PD 23      // 3*K-1
#define TBV 3.0f
#define K1 160     // padded K for GEMM1 (128 ctx + 8 xi + 24 zero)
#define PSTR 192   // p row stride (fp32)
#define N3 184     // real N of GEMM3

typedef _Float16 f16;
typedef __attribute__((ext_vector_type(8))) _Float16 f16x8;
typedef __attribute__((ext_vector_type(4))) float f32x4;

__device__ __forceinline__ void splitf(float v, f16* h, f16* l) {
    f16 hv = (f16)v;
    *h = hv;
    *l = (f16)(v - (float)hv);
}

__device__ __forceinline__ void gload16(const void* g, void* l) {
    __builtin_amdgcn_global_load_lds(
        (const __attribute__((address_space(1))) unsigned int*)g,
        (__attribute__((address_space(3))) unsigned int*)l, 16, 0, 0);
}

// ---------------- prep ----------------
__global__ __launch_bounds__(256)
void prep_x_kernel(const float* __restrict__ in, float* __restrict__ x,
                   float* __restrict__ ldet,
                   f16* __restrict__ A1h, f16* __restrict__ A1l, int rows) {
    int idx = blockIdx.x * 256 + threadIdx.x;
    if (idx < rows * FDIM) {
        int r = idx >> 4, f = idx & 15;
        float v = fminf(fmaxf(in[idx], -1.f), 1.f);
        x[idx] = v;
        if (f & 1) {   // layer0: idn = odd features
            size_t o = (size_t)r * K1 + 128 + (f >> 1);
            f16 hv, lv; splitf(v, &hv, &lv);
            A1h[o] = hv; A1l[o] = lv;
        }
    }
    if (idx < rows) ldet[idx] = 0.f;
}

__global__ __launch_bounds__(256)
void prep_ctx_kernel(const float* __restrict__ ctx,
                     f16* __restrict__ A1h, f16* __restrict__ A1l, int rows) {
    int total = rows * K1;
    for (int i = blockIdx.x * 256 + threadIdx.x; i < total; i += gridDim.x * 256) {
        int r = i / K1, c = i - r * K1;
        if (c < CDIM) {
            f16 hv, lv; splitf(ctx[(size_t)r * CDIM + c], &hv, &lv);
            A1h[i] = hv; A1l[i] = lv;
        } else if (c >= 136) { A1h[i] = (f16)0.f; A1l[i] = (f16)0.f; }
    }
}

// ---------------- weight conversion (transposed to [N][K], split) ----------------
__global__ __launch_bounds__(256)
void conv_w1_kernel(const float* __restrict__ W1,
                    f16* __restrict__ Wh, f16* __restrict__ Wl) {
    int idx = blockIdx.x * 256 + threadIdx.x;
    if (idx >= NL * HDIM * K1) return;
    int l = idx / (HDIM * K1);
    int rem = idx - l * HDIM * K1;
    int n = rem / K1;
    int k = rem - n * K1;
    int row = (k < 128) ? (8 + k) : ((k < 136) ? (k - 128) : -1);
    float v = (row >= 0) ? W1[((size_t)l * 136 + row) * HDIM + n] : 0.f;
    f16 hv, lv; splitf(v, &hv, &lv);
    Wh[idx] = hv; Wl[idx] = lv;
}

__global__ __launch_bounds__(256)
void conv_w2_kernel(const float* __restrict__ W2,
                    f16* __restrict__ Wh, f16* __restrict__ Wl) {
    int idx = blockIdx.x * 256 + threadIdx.x;
    if (idx >= NL * HDIM * HDIM) return;
    int l = idx / (HDIM * HDIM);
    int rem = idx - l * HDIM * HDIM;
    int n = rem >> 8;
    int k = rem & 255;
    f16 hv, lv; splitf(W2[((size_t)l * HDIM + k) * HDIM + n], &hv, &lv);
    Wh[idx] = hv; Wl[idx] = lv;
}

__global__ __launch_bounds__(256)
void conv_w3_kernel(const float* __restrict__ W3,
                    f16* __restrict__ Wh, f16* __restrict__ Wl) {
    int idx = blockIdx.x * 256 + threadIdx.x;
    if (idx >= NL * HDIM * HDIM) return;
    int l = idx / (HDIM * HDIM);
    int rem = idx - l * HDIM * HDIM;
    int n = rem >> 8;
    int k = rem & 255;
    float v = (n < N3) ? W3[((size_t)l * HDIM + k) * N3 + n] : 0.f;
    f16 hv, lv; splitf(v, &hv, &lv);
    Wh[idx] = hv; Wl[idx] = lv;
}

// ---------------- split-f16 MFMA GEMM: out = [relu](A @ Bw^T + bias) ----------------
// A = Ah+Al: rows x KDIM. Bw = Bh+Bl: 256 x KDIM (N-major). 128x128 tile, BK=32.
// acc += Ah*Bh + Ah*Bl + Al*Bh   (ll term dropped, ~2^-22 rel)
// OUTMODE 0: split f16 + relu, stride 256. OUTMODE 1: fp32, stride PSTR, col<N3.
template<int KDIM, int OUTMODE>
__global__ __launch_bounds__(256)
void mm_kernel(const f16* __restrict__ Ah, const f16* __restrict__ Al,
               const f16* __restrict__ Bh, const f16* __restrict__ Bl,
               const float* __restrict__ bias,
               void* __restrict__ out_h, void* __restrict__ out_l) {
    __shared__ f16 sAh[128 * 32];
    __shared__ f16 sAl[128 * 32];
    __shared__ f16 sBh[128 * 32];
    __shared__ f16 sBl[128 * 32];
    const int tid = threadIdx.x;
    const int lane = tid & 63;
    const int w = tid >> 6;
    const int wr = w >> 1, wc = w & 1;
    const int lr = lane & 15, lh = lane >> 4;
    const int r0 = blockIdx.x * 128;
    const int c0 = blockIdx.y * 128;
    const int rowst = tid >> 2, segst = tid & 3;

    f32x4 acc[4][4];
    #pragma unroll
    for (int i = 0; i < 4; ++i)
        #pragma unroll
        for (int j = 0; j < 4; ++j) acc[i][j] = (f32x4){0.f, 0.f, 0.f, 0.f};

    const size_t aoff = (size_t)(r0 + rowst) * KDIM + segst * 8;
    const size_t boff = (size_t)(c0 + rowst) * KDIM + segst * 8;
    const size_t half = (size_t)64 * KDIM;

    for (int kt = 0; kt < KDIM / 32; ++kt) {
        const int k0 = kt * 32;
        gload16(Ah + aoff + k0, &sAh[tid * 8]);
        gload16(Ah + aoff + half + k0, &sAh[(tid + 256) * 8]);
        gload16(Al + aoff + k0, &sAl[tid * 8]);
        gload16(Al + aoff + half + k0, &sAl[(tid + 256) * 8]);
        gload16(Bh + boff + k0, &sBh[tid * 8]);
        gload16(Bh + boff + half + k0, &sBh[(tid + 256) * 8]);
        gload16(Bl + boff + k0, &sBl[tid * 8]);
        gload16(Bl + boff + half + k0, &sBl[(tid + 256) * 8]);
        __syncthreads();
        f16x8 fah[4], fal[4], fbh[4], fbl[4];
        #pragma unroll
        for (int i = 0; i < 4; ++i) {
            int o = (wr * 64 + i * 16 + lr) * 32 + lh * 8;
            fah[i] = *(const f16x8*)&sAh[o];
            fal[i] = *(const f16x8*)&sAl[o];
        }
        #pragma unroll
        for (int j = 0; j < 4; ++j) {
            int o = (wc * 64 + j * 16 + lr) * 32 + lh * 8;
            fbh[j] = *(const f16x8*)&sBh[o];
            fbl[j] = *(const f16x8*)&sBl[o];
        }
        #pragma unroll
        for (int i = 0; i < 4; ++i)
            #pragma unroll
            for (int j = 0; j < 4; ++j) {
                acc[i][j] = __builtin_amdgcn_mfma_f32_16x16x32_f16(
                    fah[i], fbh[j], acc[i][j], 0, 0, 0);
                acc[i][j] = __builtin_amdgcn_mfma_f32_16x16x32_f16(
                    fah[i], fbl[j], acc[i][j], 0, 0, 0);
                acc[i][j] = __builtin_amdgcn_mfma_f32_16x16x32_f16(
                    fal[i], fbh[j], acc[i][j], 0, 0, 0);
            }
        __syncthreads();
    }

    #pragma unroll
    for (int i = 0; i < 4; ++i) {
        #pragma unroll
        for (int j = 0; j < 4; ++j) {
            const int col = c0 + wc * 64 + j * 16 + lr;
            const int rowb = r0 + wr * 64 + i * 16 + lh * 4;
            if (OUTMODE == 0) {
                const float bv = bias[col];
                f16* oh = (f16*)out_h;
                f16* ol = (f16*)out_l;
                #pragma unroll
                for (int q = 0; q < 4; ++q) {
                    float v = fmaxf(acc[i][j][q] + bv, 0.f);
                    f16 hv, lv; splitf(v, &hv, &lv);
                    oh[(size_t)(rowb + q) * HDIM + col] = hv;
                    ol[(size_t)(rowb + q) * HDIM + col] = lv;
                }
            } else {
                if (col < N3) {
                    const float bv = bias[col];
                    float* o = (float*)out_h;
                    #pragma unroll
                    for (int q = 0; q < 4; ++q)
                        o[(size_t)(rowb + q) * PSTR + col] = acc[i][j][q] + bv;
                }
            }
        }
    }
}

// ---------------- spline ----------------
__device__ __forceinline__ float softplusf(float v) {
    return fmaxf(v, 0.f) + log1pf(expf(-fabsf(v)));
}

__global__ __launch_bounds__(256)
void spline_kernel(const float* __restrict__ x_old, const float* __restrict__ p,
                   const int* __restrict__ perms,
                   float* __restrict__ x_new, float* __restrict__ ldet,
                   f16* __restrict__ A1h, f16* __restrict__ A1l,
                   float* __restrict__ out_final,
                   int layer, int row_base) {
    int tid = threadIdx.x;
    int f = tid & 15;
    int r = blockIdx.x * 16 + (tid >> 4);
    int g = (layer < NL - 1) ? perms[layer * FDIM + f] : f;
    float val;
    float ld = 0.f;
    if ((g & 1) == (layer & 1)) {   // transformed feature
        int t = g >> 1;
        float xin = x_old[(size_t)r * FDIM + g];
        const float* pp = &p[(size_t)r * PSTR + t * PD];
        float uw[KBINS], uh[KBINS], ud[KBINS - 1];
        #pragma unroll
        for (int k = 0; k < KBINS; ++k) uw[k] = pp[k];
        #pragma unroll
        for (int k = 0; k < KBINS; ++k) uh[k] = pp[KBINS + k];
        #pragma unroll
        for (int k = 0; k < KBINS - 1; ++k) ud[k] = pp[2 * KBINS + k];

        float mw = uw[0];
        #pragma unroll
        for (int k = 1; k < KBINS; ++k) mw = fmaxf(mw, uw[k]);
        float ew[KBINS], sw = 0.f;
        #pragma unroll
        for (int k = 0; k < KBINS; ++k) { ew[k] = expf(uw[k] - mw); sw += ew[k]; }
        float cw[KBINS + 1];
        cw[0] = -TBV;
        {
            float s = 0.f, inv = 1.f / sw;
            #pragma unroll
            for (int k = 0; k < KBINS; ++k) {
                float wk = 0.001f + (1.f - 0.001f * KBINS) * ew[k] * inv;
                s += wk;
                cw[k + 1] = 2.f * TBV * s - TBV;
            }
            cw[KBINS] = TBV;
        }
        float mh = uh[0];
        #pragma unroll
        for (int k = 1; k < KBINS; ++k) mh = fmaxf(mh, uh[k]);
        float eh[KBINS], sh = 0.f;
        #pragma unroll
        for (int k = 0; k < KBINS; ++k) { eh[k] = expf(uh[k] - mh); sh += eh[k]; }
        float ch[KBINS + 1];
        ch[0] = -TBV;
        {
            float s = 0.f, inv = 1.f / sh;
            #pragma unroll
            for (int k = 0; k < KBINS; ++k) {
                float hk = 0.001f + (1.f - 0.001f * KBINS) * eh[k] * inv;
                s += hk;
                ch[k + 1] = 2.f * TBV * s - TBV;
            }
            ch[KBINS] = TBV;
        }
        float d[KBINS + 1];
        d[0] = 1.f; d[KBINS] = 1.f;
        #pragma unroll
        for (int k = 1; k < KBINS; ++k) d[k] = 0.001f + softplusf(ud[k - 1]);

        bool inside = (xin >= -TBV) && (xin <= TBV);
        float xs = fminf(fmaxf(xin, -TBV), TBV);
        int idx = 0;
        #pragma unroll
        for (int k = 1; k < KBINS; ++k) idx += (xs >= cw[k]) ? 1 : 0;
        float x0 = cw[0], x1 = cw[1], y0 = ch[0], y1 = ch[1], d0 = d[0], d1 = d[1];
        #pragma unroll
        for (int k = 0; k < KBINS; ++k) {
            if (idx == k) { x0 = cw[k]; x1 = cw[k + 1]; y0 = ch[k]; y1 = ch[k + 1]; d0 = d[k]; d1 = d[k + 1]; }
        }
        float bw = x1 - x0, bh = y1 - y0;
        float delta = bh / bw;
        float th = (xs - x0) / bw;
        float th1m = th * (1.f - th);
        float num = bh * (delta * th * th + d0 * th1m);
        float den = delta + (d0 + d1 - 2.f * delta) * th1m;
        float y = y0 + num / den;
        float omth = 1.f - th;
        float dnum = delta * delta * (d1 * th * th + 2.f * delta * th1m + d0 * omth * omth);
        float ldv = logf(dnum) - 2.f * logf(den);
        val = inside ? y : xin;
        ld = inside ? ldv : 0.f;
    } else {
        val = x_old[(size_t)r * FDIM + g];
    }
    #pragma unroll
    for (int o = 1; o < 16; o <<= 1) ld += __shfl_xor(ld, o, 64);

    if (layer == NL - 1) {
        int gr = row_base + r;
        out_final[(size_t)gr * FDIM + f] = fminf(fmaxf(val, -1.f), 1.f);
        if (f == 0) out_final[(size_t)BATCH * FDIM + gr] = ldet[r] + ld;
    } else {
        x_new[(size_t)r * FDIM + f] = val;
        // refresh A1 xi columns for next layer: idn_next parity = layer&1
        if ((f & 1) == (layer & 1)) {
            size_t o = (size_t)r * K1 + 128 + (f >> 1);
            f16 hv, lv; splitf(val, &hv, &lv);
            A1h[o] = hv; A1l[o] = lv;
        }
        if (f == 0) ldet[r] += ld;
    }
}

extern "C" void kernel_launch(void* const* d_in, const int* in_sizes, int n_in,
                              void* d_out, int out_size, void* d_ws, size_t ws_size,
                              hipStream_t stream) {
    (void)in_sizes; (void)n_in; (void)out_size;
    const float* inputs  = (const float*)d_in[0];
    const float* context = (const float*)d_in[1];
    const float* W1 = (const float*)d_in[2];
    const float* b1 = (const float*)d_in[3];
    const float* W2 = (const float*)d_in[4];
    const float* b2 = (const float*)d_in[5];
    const float* W3 = (const float*)d_in[6];
    const float* b3 = (const float*)d_in[7];
    const int*   perms = (const int*)d_in[8];
    float* out = (float*)d_out;

    char* ws = (char*)d_ws;
    f16* W1h = (f16*)ws;
    f16* W1l = W1h + (size_t)NL * HDIM * K1;
    f16* W2h = W1l + (size_t)NL * HDIM * K1;
    f16* W2l = W2h + (size_t)NL * HDIM * HDIM;
    f16* W3h = W2l + (size_t)NL * HDIM * HDIM;
    f16* W3l = W3h + (size_t)NL * HDIM * HDIM;
    char* dyn = (char*)(W3l + (size_t)NL * HDIM * HDIM);
    size_t fixed = (size_t)(dyn - ws);

    // per-row bytes: x_a 64 + x_b 64 + ldet 4 + A1 2*320 + h2 2*512 + U 1024
    const size_t per_row = 64 + 64 + 4 + 640 + 1024 + 1024;
    int rows = BATCH;
    while ((size_t)rows * per_row + fixed > ws_size && rows > 128) rows >>= 1;

    {   // weight conversion, once per launch
        int n1 = NL * HDIM * K1;
        conv_w1_kernel<<<(n1 + 255) / 256, 256, 0, stream>>>(W1, W1h, W1l);
        int n2 = NL * HDIM * HDIM;
        conv_w2_kernel<<<(n2 + 255) / 256, 256, 0, stream>>>(W2, W2h, W2l);
        conv_w3_kernel<<<(n2 + 255) / 256, 256, 0, stream>>>(W3, W3h, W3l);
    }

    for (int base = 0; base < BATCH; base += rows) {
        float* x_a  = (float*)dyn;
        float* x_b  = x_a + (size_t)rows * FDIM;
        float* ldet = x_b + (size_t)rows * FDIM;
        f16* A1h = (f16*)(ldet + rows);
        f16* A1l = A1h + (size_t)rows * K1;
        f16* h2h = A1l + (size_t)rows * K1;
        f16* h2l = h2h + (size_t)rows * HDIM;
        char* U = (char*)(h2l + (size_t)rows * HDIM);
        f16* h1h = (f16*)U;
        f16* h1l = h1h + (size_t)rows * HDIM;
        float* p = (float*)U;

        prep_x_kernel<<<(rows * FDIM + 255) / 256, 256, 0, stream>>>(
            inputs + (size_t)base * FDIM, x_a, ldet, A1h, A1l, rows);
        {
            int total = rows * K1;
            int blocks = (total + 255) / 256;
            if (blocks > 4096) blocks = 4096;
            prep_ctx_kernel<<<blocks, 256, 0, stream>>>(
                context + (size_t)base * CDIM, A1h, A1l, rows);
        }

        float* xo = x_a;
        float* xn = x_b;
        for (int l = 0; l < NL; ++l) {
            mm_kernel<K1, 0><<<dim3(rows / 128, 2), 256, 0, stream>>>(
                A1h, A1l, W1h + (size_t)l * HDIM * K1, W1l + (size_t)l * HDIM * K1,
                b1 + (size_t)l * HDIM, h1h, h1l);
            mm_kernel<HDIM, 0><<<dim3(rows / 128, 2), 256, 0, stream>>>(
                h1h, h1l, W2h + (size_t)l * HDIM * HDIM, W2l + (size_t)l * HDIM * HDIM,
                b2 + (size_t)l * HDIM, h2h, h2l);
            mm_kernel<HDIM, 1><<<dim3(rows / 128, 2), 256, 0, stream>>>(
                h2h, h2l, W3h + (size_t)l * HDIM * HDIM, W3l + (size_t)l * HDIM * HDIM,
                b3 + (size_t)l * N3, p, nullptr);
            spline_kernel<<<rows / 16, 256, 0, stream>>>(
                xo, p, perms, xn, ldet, A1h, A1l, out, l, base);
            float* tmp = xo; xo = xn; xn = tmp;
        }
    }
}

// Round 4
// 1126.860 us; speedup vs baseline: 2.7741x; 1.1304x over previous
//
#include <hip/hip_runtime.h>
#include <math.h>

#define BATCH 65536
#define FDIM 16
#define CDIM 128
#define HDIM 256
#define NL 8
#define KBINS 8
#define TDIM 8
#define PD 23
#define TBV 3.0f
#define K1 160      // GEMM1 K: 128 ctx + 8 xi + 24 zero
#define N3 184      // real N of GEMM3
#define N3P 192     // padded N of GEMM3
#define PSTR 197    // p LDS row stride (f32 words, coprime with 32)

typedef _Float16 f16;
typedef __attribute__((ext_vector_type(8))) _Float16 f16x8;
typedef __attribute__((ext_vector_type(4))) float f32x4;

__device__ __forceinline__ void splitf(float v, f16* h, f16* l) {
    f16 hv = (f16)v;
    *h = hv;
    *l = (f16)(v - (float)hv);
}

// ---------------- weight conversion (transposed to [N][K], split hi/lo) ----
__global__ __launch_bounds__(256)
void conv_w1_kernel(const float* __restrict__ W1,
                    f16* __restrict__ Wh, f16* __restrict__ Wl) {
    int idx = blockIdx.x * 256 + threadIdx.x;
    if (idx >= NL * HDIM * K1) return;
    int l = idx / (HDIM * K1);
    int rem = idx - l * HDIM * K1;
    int n = rem / K1;
    int k = rem - n * K1;
    int row = (k < 128) ? (8 + k) : ((k < 136) ? (k - 128) : -1);
    float v = (row >= 0) ? W1[((size_t)l * 136 + row) * HDIM + n] : 0.f;
    f16 hv, lv; splitf(v, &hv, &lv);
    Wh[idx] = hv; Wl[idx] = lv;
}

__global__ __launch_bounds__(256)
void conv_w2_kernel(const float* __restrict__ W2,
                    f16* __restrict__ Wh, f16* __restrict__ Wl) {
    int idx = blockIdx.x * 256 + threadIdx.x;
    if (idx >= NL * HDIM * HDIM) return;
    int l = idx / (HDIM * HDIM);
    int rem = idx - l * HDIM * HDIM;
    int n = rem >> 8;
    int k = rem & 255;
    f16 hv, lv; splitf(W2[((size_t)l * HDIM + k) * HDIM + n], &hv, &lv);
    Wh[idx] = hv; Wl[idx] = lv;
}

__global__ __launch_bounds__(256)
void conv_w3_kernel(const float* __restrict__ W3,
                    f16* __restrict__ Wh, f16* __restrict__ Wl) {
    int idx = blockIdx.x * 256 + threadIdx.x;
    if (idx >= NL * N3P * HDIM) return;
    int l = idx / (N3P * HDIM);
    int rem = idx - l * N3P * HDIM;
    int n = rem >> 8;
    int k = rem & 255;
    float v = (n < N3) ? W3[((size_t)l * HDIM + k) * N3 + n] : 0.f;
    f16 hv, lv; splitf(v, &hv, &lv);
    Wh[idx] = hv; Wl[idx] = lv;
}

__device__ __forceinline__ float softplusf(float v) {
    return fmaxf(v, 0.f) + log1pf(expf(-fabsf(v)));
}

// ---------------- fused flow kernel ----------------
// 64 rows per WG, 256 threads (4 waves). All 8 layers in one dispatch.
// sH: two 32KB f16 planes (hi/lo), XOR-swizzled [row][k] (row<64, k<256).
// Overlaid by sP (fp32 p buffer) between barriers.
__global__ __launch_bounds__(256, 2)
void flow_kernel(const float* __restrict__ in, const float* __restrict__ ctx,
                 const f16* __restrict__ W1h, const f16* __restrict__ W1l,
                 const f16* __restrict__ W2h, const f16* __restrict__ W2l,
                 const f16* __restrict__ W3h, const f16* __restrict__ W3l,
                 const float* __restrict__ b1, const float* __restrict__ b2,
                 const float* __restrict__ b3, const int* __restrict__ perms,
                 float* __restrict__ out) {
    __shared__ f16 sH[2 * 64 * 256];            // 64KB
    __shared__ float sX[2][64][17];
    __shared__ float sY[64][9];
    __shared__ float sLdp[4][64];
    __shared__ float sLdet[64];
    __shared__ int   sPerm[(NL - 1) * FDIM];

    const int tid = threadIdx.x;
    const int lane = tid & 63;
    const int w = tid >> 6;
    const int lr = lane & 15, lh = lane >> 4;
    const int rbase = blockIdx.x * 64;
    float* sP = (float*)sH;                      // 64 x PSTR fp32 overlay

    // swizzled LDS helpers: byte = (row*512 + k*2) ^ ((row&7)<<4)
    auto lds_rd8 = [&](int plane, int row, int k) -> f16x8 {
        int byte = ((row << 9) + (k << 1)) ^ ((row & 7) << 4);
        return *(const f16x8*)((const char*)sH + plane * 32768 + byte);
    };
    auto lds_wr8 = [&](int plane, int row, int k, f16x8 v) {
        int byte = ((row << 9) + (k << 1)) ^ ((row & 7) << 4);
        *(f16x8*)((char*)sH + plane * 32768 + byte) = v;
    };
    auto lds_wr1 = [&](int plane, int row, int k, f16 v) {
        int byte = ((row << 9) + (k << 1)) ^ ((row & 7) << 4);
        *(f16*)((char*)sH + plane * 32768 + byte) = v;
    };

    // ---- init: x block, ldet, perms, ctx->regs ----
    {
        int r = tid >> 2, c4 = (tid & 3) * 4;
        float4 v = *(const float4*)&in[(size_t)(rbase + r) * FDIM + c4];
        sX[0][r][c4 + 0] = fminf(fmaxf(v.x, -1.f), 1.f);
        sX[0][r][c4 + 1] = fminf(fmaxf(v.y, -1.f), 1.f);
        sX[0][r][c4 + 2] = fminf(fmaxf(v.z, -1.f), 1.f);
        sX[0][r][c4 + 3] = fminf(fmaxf(v.w, -1.f), 1.f);
    }
    if (tid < 64) sLdet[tid] = 0.f;
    if (tid < (NL - 1) * FDIM) sPerm[tid] = perms[tid];

    f16x8 ctxh[4], ctxl[4];
    {
        int r = tid >> 2, c0 = (tid & 3) * 32;
        const float* cp = &ctx[(size_t)(rbase + r) * CDIM + c0];
        #pragma unroll
        for (int s = 0; s < 4; ++s) {
            f16x8 h8, l8;
            #pragma unroll
            for (int e = 0; e < 8; ++e) {
                float v = cp[s * 8 + e];
                f16 hv, lv; splitf(v, &hv, &lv);
                h8[e] = hv; l8[e] = lv;
            }
            ctxh[s] = h8; ctxl[s] = l8;
        }
    }

    int cur = 0;
    for (int l = 0; l < NL; ++l) {
        __syncthreads();
        // ---- stage A1 into sH: ctx (k 0..127) + xi (128..135) + zeros ----
        {
            int r = tid >> 2, c0 = (tid & 3) * 32;
            #pragma unroll
            for (int s = 0; s < 4; ++s) {
                lds_wr8(0, r, c0 + s * 8, ctxh[s]);
                lds_wr8(1, r, c0 + s * 8, ctxl[s]);
            }
        }
        if (tid < 64) {
            int r = tid, off = 1 - (l & 1);
            f16x8 h8, l8, z;
            #pragma unroll
            for (int k = 0; k < 8; ++k) {
                float v = sX[cur][r][2 * k + off];
                f16 hv, lv; splitf(v, &hv, &lv);
                h8[k] = hv; l8[k] = lv; z[k] = (f16)0.f;
            }
            lds_wr8(0, r, 128, h8); lds_wr8(1, r, 128, l8);
            lds_wr8(0, r, 136, z);  lds_wr8(1, r, 136, z);
            lds_wr8(0, r, 144, z);  lds_wr8(1, r, 144, z);
            lds_wr8(0, r, 152, z);  lds_wr8(1, r, 152, z);
        }
        __syncthreads();

        f32x4 acc[4][4];
        // ================= GEMM1: 256 cols, K=160 =================
        #pragma unroll
        for (int i = 0; i < 4; ++i)
            #pragma unroll
            for (int j = 0; j < 4; ++j) acc[i][j] = (f32x4){0.f, 0.f, 0.f, 0.f};
        for (int kt = 0; kt < 5; ++kt) {
            int k0 = kt * 32 + lh * 8;
            f16x8 bh[4], bl[4], ah[4], al[4];
            #pragma unroll
            for (int j = 0; j < 4; ++j) {
                size_t o = (size_t)(l * HDIM + w * 64 + j * 16 + lr) * K1 + k0;
                bh[j] = *(const f16x8*)(W1h + o);
                bl[j] = *(const f16x8*)(W1l + o);
            }
            #pragma unroll
            for (int i = 0; i < 4; ++i) {
                ah[i] = lds_rd8(0, i * 16 + lr, k0);
                al[i] = lds_rd8(1, i * 16 + lr, k0);
            }
            #pragma unroll
            for (int i = 0; i < 4; ++i)
                #pragma unroll
                for (int j = 0; j < 4; ++j) {
                    acc[i][j] = __builtin_amdgcn_mfma_f32_16x16x32_f16(ah[i], bh[j], acc[i][j], 0, 0, 0);
                    acc[i][j] = __builtin_amdgcn_mfma_f32_16x16x32_f16(ah[i], bl[j], acc[i][j], 0, 0, 0);
                    acc[i][j] = __builtin_amdgcn_mfma_f32_16x16x32_f16(al[i], bh[j], acc[i][j], 0, 0, 0);
                }
        }
        __syncthreads();
        // h1 = relu(acc + b1) -> split into sH
        #pragma unroll
        for (int j = 0; j < 4; ++j) {
            int col = w * 64 + j * 16 + lr;
            float bv = b1[l * HDIM + col];
            #pragma unroll
            for (int i = 0; i < 4; ++i)
                #pragma unroll
                for (int q = 0; q < 4; ++q) {
                    float v = fmaxf(acc[i][j][q] + bv, 0.f);
                    f16 hv, lv; splitf(v, &hv, &lv);
                    int row = i * 16 + lh * 4 + q;
                    lds_wr1(0, row, col, hv);
                    lds_wr1(1, row, col, lv);
                }
        }
        __syncthreads();

        // ================= GEMM2: 256 cols, K=256 =================
        #pragma unroll
        for (int i = 0; i < 4; ++i)
            #pragma unroll
            for (int j = 0; j < 4; ++j) acc[i][j] = (f32x4){0.f, 0.f, 0.f, 0.f};
        for (int kt = 0; kt < 8; ++kt) {
            int k0 = kt * 32 + lh * 8;
            f16x8 bh[4], bl[4], ah[4], al[4];
            #pragma unroll
            for (int j = 0; j < 4; ++j) {
                size_t o = (size_t)(l * HDIM + w * 64 + j * 16 + lr) * HDIM + k0;
                bh[j] = *(const f16x8*)(W2h + o);
                bl[j] = *(const f16x8*)(W2l + o);
            }
            #pragma unroll
            for (int i = 0; i < 4; ++i) {
                ah[i] = lds_rd8(0, i * 16 + lr, k0);
                al[i] = lds_rd8(1, i * 16 + lr, k0);
            }
            #pragma unroll
            for (int i = 0; i < 4; ++i)
                #pragma unroll
                for (int j = 0; j < 4; ++j) {
                    acc[i][j] = __builtin_amdgcn_mfma_f32_16x16x32_f16(ah[i], bh[j], acc[i][j], 0, 0, 0);
                    acc[i][j] = __builtin_amdgcn_mfma_f32_16x16x32_f16(ah[i], bl[j], acc[i][j], 0, 0, 0);
                    acc[i][j] = __builtin_amdgcn_mfma_f32_16x16x32_f16(al[i], bh[j], acc[i][j], 0, 0, 0);
                }
        }
        __syncthreads();
        // h2 = relu(acc + b2) -> split into sH
        #pragma unroll
        for (int j = 0; j < 4; ++j) {
            int col = w * 64 + j * 16 + lr;
            float bv = b2[l * HDIM + col];
            #pragma unroll
            for (int i = 0; i < 4; ++i)
                #pragma unroll
                for (int q = 0; q < 4; ++q) {
                    float v = fmaxf(acc[i][j][q] + bv, 0.f);
                    f16 hv, lv; splitf(v, &hv, &lv);
                    int row = i * 16 + lh * 4 + q;
                    lds_wr1(0, row, col, hv);
                    lds_wr1(1, row, col, lv);
                }
        }
        __syncthreads();

        // ================= GEMM3: 192 cols (48/wave), K=256 =================
        f32x4 acc3[4][3];
        #pragma unroll
        for (int i = 0; i < 4; ++i)
            #pragma unroll
            for (int j = 0; j < 3; ++j) acc3[i][j] = (f32x4){0.f, 0.f, 0.f, 0.f};
        for (int kt = 0; kt < 8; ++kt) {
            int k0 = kt * 32 + lh * 8;
            f16x8 bh[3], bl[3], ah[4], al[4];
            #pragma unroll
            for (int j = 0; j < 3; ++j) {
                size_t o = (size_t)(l * N3P + w * 48 + j * 16 + lr) * HDIM + k0;
                bh[j] = *(const f16x8*)(W3h + o);
                bl[j] = *(const f16x8*)(W3l + o);
            }
            #pragma unroll
            for (int i = 0; i < 4; ++i) {
                ah[i] = lds_rd8(0, i * 16 + lr, k0);
                al[i] = lds_rd8(1, i * 16 + lr, k0);
            }
            #pragma unroll
            for (int i = 0; i < 4; ++i)
                #pragma unroll
                for (int j = 0; j < 3; ++j) {
                    acc3[i][j] = __builtin_amdgcn_mfma_f32_16x16x32_f16(ah[i], bh[j], acc3[i][j], 0, 0, 0);
                    acc3[i][j] = __builtin_amdgcn_mfma_f32_16x16x32_f16(ah[i], bl[j], acc3[i][j], 0, 0, 0);
                    acc3[i][j] = __builtin_amdgcn_mfma_f32_16x16x32_f16(al[i], bh[j], acc3[i][j], 0, 0, 0);
                }
        }
        __syncthreads();
        // p = acc3 + b3 -> sP (fp32, stride PSTR)
        #pragma unroll
        for (int j = 0; j < 3; ++j) {
            int col = w * 48 + j * 16 + lr;
            float bv = (col < N3) ? b3[l * N3 + col] : 0.f;
            #pragma unroll
            for (int i = 0; i < 4; ++i)
                #pragma unroll
                for (int q = 0; q < 4; ++q) {
                    int row = i * 16 + lh * 4 + q;
                    sP[row * PSTR + col] = acc3[i][j][q] + bv;
                }
        }
        __syncthreads();

        // ================= spline: wave w handles t = 2w, 2w+1 =================
        {
            int r = tid & 63, t2 = tid >> 6;
            float ldsum = 0.f;
            #pragma unroll
            for (int dt = 0; dt < 2; ++dt) {
                int t = t2 * 2 + dt;
                float xin = sX[cur][r][2 * t + (l & 1)];
                const float* pp = &sP[r * PSTR + t * PD];
                float uw[KBINS], uh[KBINS], ud[KBINS - 1];
                #pragma unroll
                for (int k = 0; k < KBINS; ++k) uw[k] = pp[k];
                #pragma unroll
                for (int k = 0; k < KBINS; ++k) uh[k] = pp[KBINS + k];
                #pragma unroll
                for (int k = 0; k < KBINS - 1; ++k) ud[k] = pp[2 * KBINS + k];

                float mw = uw[0];
                #pragma unroll
                for (int k = 1; k < KBINS; ++k) mw = fmaxf(mw, uw[k]);
                float ew[KBINS], swv = 0.f;
                #pragma unroll
                for (int k = 0; k < KBINS; ++k) { ew[k] = expf(uw[k] - mw); swv += ew[k]; }
                float cw[KBINS + 1];
                cw[0] = -TBV;
                {
                    float s = 0.f, inv = 1.f / swv;
                    #pragma unroll
                    for (int k = 0; k < KBINS; ++k) {
                        float wk = 0.001f + (1.f - 0.001f * KBINS) * ew[k] * inv;
                        s += wk;
                        cw[k + 1] = 2.f * TBV * s - TBV;
                    }
                    cw[KBINS] = TBV;
                }
                float mh = uh[0];
                #pragma unroll
                for (int k = 1; k < KBINS; ++k) mh = fmaxf(mh, uh[k]);
                float eh[KBINS], shv = 0.f;
                #pragma unroll
                for (int k = 0; k < KBINS; ++k) { eh[k] = expf(uh[k] - mh); shv += eh[k]; }
                float ch[KBINS + 1];
                ch[0] = -TBV;
                {
                    float s = 0.f, inv = 1.f / shv;
                    #pragma unroll
                    for (int k = 0; k < KBINS; ++k) {
                        float hk = 0.001f + (1.f - 0.001f * KBINS) * eh[k] * inv;
                        s += hk;
                        ch[k + 1] = 2.f * TBV * s - TBV;
                    }
                    ch[KBINS] = TBV;
                }
                float d[KBINS + 1];
                d[0] = 1.f; d[KBINS] = 1.f;
                #pragma unroll
                for (int k = 1; k < KBINS; ++k) d[k] = 0.001f + softplusf(ud[k - 1]);

                bool inside = (xin >= -TBV) && (xin <= TBV);
                float xs = fminf(fmaxf(xin, -TBV), TBV);
                int idx = 0;
                #pragma unroll
                for (int k = 1; k < KBINS; ++k) idx += (xs >= cw[k]) ? 1 : 0;
                float x0 = cw[0], x1 = cw[1], y0 = ch[0], y1 = ch[1], d0 = d[0], d1 = d[1];
                #pragma unroll
                for (int k = 0; k < KBINS; ++k) {
                    if (idx == k) { x0 = cw[k]; x1 = cw[k + 1]; y0 = ch[k]; y1 = ch[k + 1]; d0 = d[k]; d1 = d[k + 1]; }
                }
                float bw = x1 - x0, bh2 = y1 - y0;
                float delta = bh2 / bw;
                float th = (xs - x0) / bw;
                float th1m = th * (1.f - th);
                float num = bh2 * (delta * th * th + d0 * th1m);
                float den = delta + (d0 + d1 - 2.f * delta) * th1m;
                float y = y0 + num / den;
                float omth = 1.f - th;
                float dnum = delta * delta * (d1 * th * th + 2.f * delta * th1m + d0 * omth * omth);
                float ldv = logf(dnum) - 2.f * logf(den);
                sY[r][t] = inside ? y : xin;
                ldsum += inside ? ldv : 0.f;
            }
            sLdp[t2][r] = ldsum;
        }
        __syncthreads();

        // ================= rebuild x (+perm) and ldet =================
        if (tid < 64) {
            int r = tid;
            sLdet[r] += sLdp[0][r] + sLdp[1][r] + sLdp[2][r] + sLdp[3][r];
            float xo[16];
            #pragma unroll
            for (int f = 0; f < 16; ++f) xo[f] = sX[cur][r][f];
            if (l < NL - 1) {
                #pragma unroll
                for (int f = 0; f < 16; ++f) {
                    int g = sPerm[l * FDIM + f];
                    float v = ((g & 1) == (l & 1)) ? sY[r][g >> 1] : xo[g];
                    sX[cur ^ 1][r][f] = v;
                }
            } else {
                #pragma unroll
                for (int f = 0; f < 16; ++f) {
                    float v = ((f & 1) == (l & 1)) ? sY[r][f >> 1] : xo[f];
                    out[(size_t)(rbase + r) * FDIM + f] = fminf(fmaxf(v, -1.f), 1.f);
                }
                out[(size_t)BATCH * FDIM + rbase + r] = sLdet[r];
            }
        }
        cur ^= 1;
    }
}

extern "C" void kernel_launch(void* const* d_in, const int* in_sizes, int n_in,
                              void* d_out, int out_size, void* d_ws, size_t ws_size,
                              hipStream_t stream) {
    (void)in_sizes; (void)n_in; (void)out_size; (void)ws_size;
    const float* inputs  = (const float*)d_in[0];
    const float* context = (const float*)d_in[1];
    const float* W1 = (const float*)d_in[2];
    const float* b1 = (const float*)d_in[3];
    const float* W2 = (const float*)d_in[4];
    const float* b2 = (const float*)d_in[5];
    const float* W3 = (const float*)d_in[6];
    const float* b3 = (const float*)d_in[7];
    const int*   perms = (const int*)d_in[8];
    float* out = (float*)d_out;

    f16* W1h = (f16*)d_ws;
    f16* W1l = W1h + (size_t)NL * HDIM * K1;
    f16* W2h = W1l + (size_t)NL * HDIM * K1;
    f16* W2l = W2h + (size_t)NL * HDIM * HDIM;
    f16* W3h = W2l + (size_t)NL * HDIM * HDIM;
    f16* W3l = W3h + (size_t)NL * N3P * HDIM;

    int n1 = NL * HDIM * K1;
    conv_w1_kernel<<<(n1 + 255) / 256, 256, 0, stream>>>(W1, W1h, W1l);
    int n2 = NL * HDIM * HDIM;
    conv_w2_kernel<<<(n2 + 255) / 256, 256, 0, stream>>>(W2, W2h, W2l);
    int n3 = NL * N3P * HDIM;
    conv_w3_kernel<<<(n3 + 255) / 256, 256, 0, stream>>>(W3, W3h, W3l);

    flow_kernel<<<BATCH / 64, 256, 0, stream>>>(
        inputs, context, W1h, W1l, W2h, W2l, W3h, W3l,
        b1, b2, b3, perms, out);
}

// Round 5
// 1057.623 us; speedup vs baseline: 2.9557x; 1.0655x over previous
//
#include <hip/hip_runtime.h>
#include <math.h>

#define BATCH 65536
#define FDIM 16
#define CDIM 128
#define HDIM 256
#define NL 8
#define KBINS 8
#define TDIM 8
#define PD 23
#define TBV 3.0f
#define K1 160      // GEMM1 K: 128 ctx + 8 xi + 24 zero
#define N3 184      // real N of GEMM3
#define N3P 192     // padded N of GEMM3
#define PSTR 197    // p LDS row stride (f32 words, coprime with 32)

typedef _Float16 f16;
typedef __attribute__((ext_vector_type(8))) _Float16 f16x8;
typedef __attribute__((ext_vector_type(4))) float f32x4;

__device__ __forceinline__ void splitf(float v, f16* h, f16* l) {
    f16 hv = (f16)v;
    *h = hv;
    *l = (f16)(v - (float)hv);
}

// ---------------- weight conversion (transposed to [N][K], split hi/lo) ----
__global__ __launch_bounds__(256)
void conv_w1_kernel(const float* __restrict__ W1,
                    f16* __restrict__ Wh, f16* __restrict__ Wl) {
    int idx = blockIdx.x * 256 + threadIdx.x;
    if (idx >= NL * HDIM * K1) return;
    int l = idx / (HDIM * K1);
    int rem = idx - l * HDIM * K1;
    int n = rem / K1;
    int k = rem - n * K1;
    int row = (k < 128) ? (8 + k) : ((k < 136) ? (k - 128) : -1);
    float v = (row >= 0) ? W1[((size_t)l * 136 + row) * HDIM + n] : 0.f;
    f16 hv, lv; splitf(v, &hv, &lv);
    Wh[idx] = hv; Wl[idx] = lv;
}

__global__ __launch_bounds__(256)
void conv_w2_kernel(const float* __restrict__ W2,
                    f16* __restrict__ Wh, f16* __restrict__ Wl) {
    int idx = blockIdx.x * 256 + threadIdx.x;
    if (idx >= NL * HDIM * HDIM) return;
    int l = idx / (HDIM * HDIM);
    int rem = idx - l * HDIM * HDIM;
    int n = rem >> 8;
    int k = rem & 255;
    f16 hv, lv; splitf(W2[((size_t)l * HDIM + k) * HDIM + n], &hv, &lv);
    Wh[idx] = hv; Wl[idx] = lv;
}

__global__ __launch_bounds__(256)
void conv_w3_kernel(const float* __restrict__ W3,
                    f16* __restrict__ Wh, f16* __restrict__ Wl) {
    int idx = blockIdx.x * 256 + threadIdx.x;
    if (idx >= NL * N3P * HDIM) return;
    int l = idx / (N3P * HDIM);
    int rem = idx - l * N3P * HDIM;
    int n = rem >> 8;
    int k = rem & 255;
    float v = (n < N3) ? W3[((size_t)l * HDIM + k) * N3 + n] : 0.f;
    f16 hv, lv; splitf(v, &hv, &lv);
    Wh[idx] = hv; Wl[idx] = lv;
}

__global__ __launch_bounds__(256)
void conv_ctx_kernel(const float* __restrict__ ctx,
                     f16* __restrict__ ch, f16* __restrict__ cl) {
    size_t idx = ((size_t)blockIdx.x * 256 + threadIdx.x) * 4;
    if (idx >= (size_t)BATCH * CDIM) return;
    float4 v = *(const float4*)&ctx[idx];
    f16 h, l;
    splitf(v.x, &h, &l); ch[idx + 0] = h; cl[idx + 0] = l;
    splitf(v.y, &h, &l); ch[idx + 1] = h; cl[idx + 1] = l;
    splitf(v.z, &h, &l); ch[idx + 2] = h; cl[idx + 2] = l;
    splitf(v.w, &h, &l); ch[idx + 3] = h; cl[idx + 3] = l;
}

__device__ __forceinline__ float softplusf(float v) {
    return fmaxf(v, 0.f) + log1pf(expf(-fabsf(v)));
}

// ---------------- fused flow kernel ----------------
// 64 rows per WG, 256 threads (4 waves). All 8 layers in one dispatch.
// sH: two 32KB f16 planes (hi/lo), XOR-swizzled [row][k] (row<64, k<256).
// Overlaid by sP (fp32 p buffer) between barriers.
__global__ __launch_bounds__(256, 2)
void flow_kernel(const float* __restrict__ in,
                 const f16* __restrict__ ctxh, const f16* __restrict__ ctxl,
                 const f16* __restrict__ W1h, const f16* __restrict__ W1l,
                 const f16* __restrict__ W2h, const f16* __restrict__ W2l,
                 const f16* __restrict__ W3h, const f16* __restrict__ W3l,
                 const float* __restrict__ b1, const float* __restrict__ b2,
                 const float* __restrict__ b3, const int* __restrict__ perms,
                 float* __restrict__ out) {
    __shared__ f16 sH[2 * 64 * 256];            // 64KB
    __shared__ float sX[2][64][17];
    __shared__ float sY[64][9];
    __shared__ float sLdp[4][64];
    __shared__ float sLdet[64];
    __shared__ int   sPerm[(NL - 1) * FDIM];

    const int tid = threadIdx.x;
    const int lane = tid & 63;
    const int w = tid >> 6;
    const int lr = lane & 15, lh = lane >> 4;
    const int rbase = blockIdx.x * 64;
    float* sP = (float*)sH;                      // 64 x PSTR fp32 overlay

    // swizzled LDS helpers: byte = (row*512 + k*2) ^ ((row&7)<<4)
    auto lds_rd8 = [&](int plane, int row, int k) -> f16x8 {
        int byte = ((row << 9) + (k << 1)) ^ ((row & 7) << 4);
        return *(const f16x8*)((const char*)sH + plane * 32768 + byte);
    };
    auto lds_wr8 = [&](int plane, int row, int k, f16x8 v) {
        int byte = ((row << 9) + (k << 1)) ^ ((row & 7) << 4);
        *(f16x8*)((char*)sH + plane * 32768 + byte) = v;
    };
    auto lds_wr1 = [&](int plane, int row, int k, f16 v) {
        int byte = ((row << 9) + (k << 1)) ^ ((row & 7) << 4);
        *(f16*)((char*)sH + plane * 32768 + byte) = v;
    };

    // ---- init: x block, ldet, perms ----
    {
        int r = tid >> 2, c4 = (tid & 3) * 4;
        float4 v = *(const float4*)&in[(size_t)(rbase + r) * FDIM + c4];
        sX[0][r][c4 + 0] = fminf(fmaxf(v.x, -1.f), 1.f);
        sX[0][r][c4 + 1] = fminf(fmaxf(v.y, -1.f), 1.f);
        sX[0][r][c4 + 2] = fminf(fmaxf(v.z, -1.f), 1.f);
        sX[0][r][c4 + 3] = fminf(fmaxf(v.w, -1.f), 1.f);
    }
    if (tid < 64) sLdet[tid] = 0.f;
    if (tid < (NL - 1) * FDIM) sPerm[tid] = perms[tid];

    const int srow = tid >> 2, sc0 = (tid & 3) * 4;   // ctx staging: 4 chunks
    const f16* gph = ctxh + (((size_t)(rbase + srow)) << 7) + sc0 * 8;
    const f16* gpl = ctxl + (((size_t)(rbase + srow)) << 7) + sc0 * 8;

    int cur = 0;
    for (int l = 0; l < NL; ++l) {
        // ---- (A) issue ctx plane loads (global, L2-hot) before the barrier ----
        f16x8 cbh[4], cbl[4];
        #pragma unroll
        for (int s = 0; s < 4; ++s) {
            cbh[s] = ((const f16x8*)gph)[s];
            cbl[s] = ((const f16x8*)gpl)[s];
        }
        __syncthreads();
        // ---- (B) stage A1: ctx chunks (k 0..127) ----
        #pragma unroll
        for (int s = 0; s < 4; ++s) {
            lds_wr8(0, srow, (sc0 + s) * 8, cbh[s]);
            lds_wr8(1, srow, (sc0 + s) * 8, cbl[s]);
        }
        // ---- xi (k 128..135) + zeros (136..159) ----
        if (tid < 64) {
            int r = tid, off = 1 - (l & 1);
            f16x8 h8, l8, z;
            #pragma unroll
            for (int k = 0; k < 8; ++k) {
                float v = sX[cur][r][2 * k + off];
                f16 hv, lv; splitf(v, &hv, &lv);
                h8[k] = hv; l8[k] = lv; z[k] = (f16)0.f;
            }
            lds_wr8(0, r, 128, h8); lds_wr8(1, r, 128, l8);
            lds_wr8(0, r, 136, z);  lds_wr8(1, r, 136, z);
            lds_wr8(0, r, 144, z);  lds_wr8(1, r, 144, z);
            lds_wr8(0, r, 152, z);  lds_wr8(1, r, 152, z);
        }
        __syncthreads();

        f32x4 acc[4][4];
        // ================= GEMM1: 256 cols, K=160 =================
        #pragma unroll
        for (int i = 0; i < 4; ++i)
            #pragma unroll
            for (int j = 0; j < 4; ++j) acc[i][j] = (f32x4){0.f, 0.f, 0.f, 0.f};
        for (int kt = 0; kt < 5; ++kt) {
            int k0 = kt * 32 + lh * 8;
            f16x8 bh[4], bl[4], ah[4], al[4];
            #pragma unroll
            for (int j = 0; j < 4; ++j) {
                size_t o = (size_t)(l * HDIM + w * 64 + j * 16 + lr) * K1 + k0;
                bh[j] = *(const f16x8*)(W1h + o);
                bl[j] = *(const f16x8*)(W1l + o);
            }
            #pragma unroll
            for (int i = 0; i < 4; ++i) {
                ah[i] = lds_rd8(0, i * 16 + lr, k0);
                al[i] = lds_rd8(1, i * 16 + lr, k0);
            }
            __builtin_amdgcn_s_setprio(1);
            #pragma unroll
            for (int i = 0; i < 4; ++i)
                #pragma unroll
                for (int j = 0; j < 4; ++j) {
                    acc[i][j] = __builtin_amdgcn_mfma_f32_16x16x32_f16(ah[i], bh[j], acc[i][j], 0, 0, 0);
                    acc[i][j] = __builtin_amdgcn_mfma_f32_16x16x32_f16(ah[i], bl[j], acc[i][j], 0, 0, 0);
                    acc[i][j] = __builtin_amdgcn_mfma_f32_16x16x32_f16(al[i], bh[j], acc[i][j], 0, 0, 0);
                }
            __builtin_amdgcn_s_setprio(0);
        }
        __syncthreads();
        // h1 = relu(acc + b1) -> split into sH
        #pragma unroll
        for (int j = 0; j < 4; ++j) {
            int col = w * 64 + j * 16 + lr;
            float bv = b1[l * HDIM + col];
            #pragma unroll
            for (int i = 0; i < 4; ++i)
                #pragma unroll
                for (int q = 0; q < 4; ++q) {
                    float v = fmaxf(acc[i][j][q] + bv, 0.f);
                    f16 hv, lv; splitf(v, &hv, &lv);
                    int row = i * 16 + lh * 4 + q;
                    lds_wr1(0, row, col, hv);
                    lds_wr1(1, row, col, lv);
                }
        }
        __syncthreads();

        // ================= GEMM2: 256 cols, K=256 =================
        #pragma unroll
        for (int i = 0; i < 4; ++i)
            #pragma unroll
            for (int j = 0; j < 4; ++j) acc[i][j] = (f32x4){0.f, 0.f, 0.f, 0.f};
        for (int kt = 0; kt < 8; ++kt) {
            int k0 = kt * 32 + lh * 8;
            f16x8 bh[4], bl[4], ah[4], al[4];
            #pragma unroll
            for (int j = 0; j < 4; ++j) {
                size_t o = (size_t)(l * HDIM + w * 64 + j * 16 + lr) * HDIM + k0;
                bh[j] = *(const f16x8*)(W2h + o);
                bl[j] = *(const f16x8*)(W2l + o);
            }
            #pragma unroll
            for (int i = 0; i < 4; ++i) {
                ah[i] = lds_rd8(0, i * 16 + lr, k0);
                al[i] = lds_rd8(1, i * 16 + lr, k0);
            }
            __builtin_amdgcn_s_setprio(1);
            #pragma unroll
            for (int i = 0; i < 4; ++i)
                #pragma unroll
                for (int j = 0; j < 4; ++j) {
                    acc[i][j] = __builtin_amdgcn_mfma_f32_16x16x32_f16(ah[i], bh[j], acc[i][j], 0, 0, 0);
                    acc[i][j] = __builtin_amdgcn_mfma_f32_16x16x32_f16(ah[i], bl[j], acc[i][j], 0, 0, 0);
                    acc[i][j] = __builtin_amdgcn_mfma_f32_16x16x32_f16(al[i], bh[j], acc[i][j], 0, 0, 0);
                }
            __builtin_amdgcn_s_setprio(0);
        }
        __syncthreads();
        // h2 = relu(acc + b2) -> split into sH
        #pragma unroll
        for (int j = 0; j < 4; ++j) {
            int col = w * 64 + j * 16 + lr;
            float bv = b2[l * HDIM + col];
            #pragma unroll
            for (int i = 0; i < 4; ++i)
                #pragma unroll
                for (int q = 0; q < 4; ++q) {
                    float v = fmaxf(acc[i][j][q] + bv, 0.f);
                    f16 hv, lv; splitf(v, &hv, &lv);
                    int row = i * 16 + lh * 4 + q;
                    lds_wr1(0, row, col, hv);
                    lds_wr1(1, row, col, lv);
                }
        }
        __syncthreads();

        // ================= GEMM3: 192 cols (48/wave), K=256 =================
        f32x4 acc3[4][3];
        #pragma unroll
        for (int i = 0; i < 4; ++i)
            #pragma unroll
            for (int j = 0; j < 3; ++j) acc3[i][j] = (f32x4){0.f, 0.f, 0.f, 0.f};
        for (int kt = 0; kt < 8; ++kt) {
            int k0 = kt * 32 + lh * 8;
            f16x8 bh[3], bl[3], ah[4], al[4];
            #pragma unroll
            for (int j = 0; j < 3; ++j) {
                size_t o = (size_t)(l * N3P + w * 48 + j * 16 + lr) * HDIM + k0;
                bh[j] = *(const f16x8*)(W3h + o);
                bl[j] = *(const f16x8*)(W3l + o);
            }
            #pragma unroll
            for (int i = 0; i < 4; ++i) {
                ah[i] = lds_rd8(0, i * 16 + lr, k0);
                al[i] = lds_rd8(1, i * 16 + lr, k0);
            }
            __builtin_amdgcn_s_setprio(1);
            #pragma unroll
            for (int i = 0; i < 4; ++i)
                #pragma unroll
                for (int j = 0; j < 3; ++j) {
                    acc3[i][j] = __builtin_amdgcn_mfma_f32_16x16x32_f16(ah[i], bh[j], acc3[i][j], 0, 0, 0);
                    acc3[i][j] = __builtin_amdgcn_mfma_f32_16x16x32_f16(ah[i], bl[j], acc3[i][j], 0, 0, 0);
                    acc3[i][j] = __builtin_amdgcn_mfma_f32_16x16x32_f16(al[i], bh[j], acc3[i][j], 0, 0, 0);
                }
            __builtin_amdgcn_s_setprio(0);
        }
        __syncthreads();
        // p = acc3 + b3 -> sP (fp32, stride PSTR)
        #pragma unroll
        for (int j = 0; j < 3; ++j) {
            int col = w * 48 + j * 16 + lr;
            float bv = (col < N3) ? b3[l * N3 + col] : 0.f;
            #pragma unroll
            for (int i = 0; i < 4; ++i)
                #pragma unroll
                for (int q = 0; q < 4; ++q) {
                    int row = i * 16 + lh * 4 + q;
                    sP[row * PSTR + col] = acc3[i][j][q] + bv;
                }
        }
        __syncthreads();

        // ================= spline: wave w handles t = 2w, 2w+1 =================
        {
            int r = tid & 63, t2 = tid >> 6;
            float ldsum = 0.f;
            #pragma unroll
            for (int dt = 0; dt < 2; ++dt) {
                int t = t2 * 2 + dt;
                float xin = sX[cur][r][2 * t + (l & 1)];
                const float* pp = &sP[r * PSTR + t * PD];
                float uw[KBINS], uh[KBINS], ud[KBINS - 1];
                #pragma unroll
                for (int k = 0; k < KBINS; ++k) uw[k] = pp[k];
                #pragma unroll
                for (int k = 0; k < KBINS; ++k) uh[k] = pp[KBINS + k];
                #pragma unroll
                for (int k = 0; k < KBINS - 1; ++k) ud[k] = pp[2 * KBINS + k];

                float mw = uw[0];
                #pragma unroll
                for (int k = 1; k < KBINS; ++k) mw = fmaxf(mw, uw[k]);
                float ew[KBINS], swv = 0.f;
                #pragma unroll
                for (int k = 0; k < KBINS; ++k) { ew[k] = expf(uw[k] - mw); swv += ew[k]; }
                float cw[KBINS + 1];
                cw[0] = -TBV;
                {
                    float s = 0.f, inv = 1.f / swv;
                    #pragma unroll
                    for (int k = 0; k < KBINS; ++k) {
                        float wk = 0.001f + (1.f - 0.001f * KBINS) * ew[k] * inv;
                        s += wk;
                        cw[k + 1] = 2.f * TBV * s - TBV;
                    }
                    cw[KBINS] = TBV;
                }
                float mh = uh[0];
                #pragma unroll
                for (int k = 1; k < KBINS; ++k) mh = fmaxf(mh, uh[k]);
                float eh[KBINS], shv = 0.f;
                #pragma unroll
                for (int k = 0; k < KBINS; ++k) { eh[k] = expf(uh[k] - mh); shv += eh[k]; }
                float ch[KBINS + 1];
                ch[0] = -TBV;
                {
                    float s = 0.f, inv = 1.f / shv;
                    #pragma unroll
                    for (int k = 0; k < KBINS; ++k) {
                        float hk = 0.001f + (1.f - 0.001f * KBINS) * eh[k] * inv;
                        s += hk;
                        ch[k + 1] = 2.f * TBV * s - TBV;
                    }
                    ch[KBINS] = TBV;
                }
                float d[KBINS + 1];
                d[0] = 1.f; d[KBINS] = 1.f;
                #pragma unroll
                for (int k = 1; k < KBINS; ++k) d[k] = 0.001f + softplusf(ud[k - 1]);

                bool inside = (xin >= -TBV) && (xin <= TBV);
                float xs = fminf(fmaxf(xin, -TBV), TBV);
                int idx = 0;
                #pragma unroll
                for (int k = 1; k < KBINS; ++k) idx += (xs >= cw[k]) ? 1 : 0;
                float x0 = cw[0], x1 = cw[1], y0 = ch[0], y1 = ch[1], d0 = d[0], d1 = d[1];
                #pragma unroll
                for (int k = 0; k < KBINS; ++k) {
                    if (idx == k) { x0 = cw[k]; x1 = cw[k + 1]; y0 = ch[k]; y1 = ch[k + 1]; d0 = d[k]; d1 = d[k + 1]; }
                }
                float bw = x1 - x0, bh2 = y1 - y0;
                float delta = bh2 / bw;
                float th = (xs - x0) / bw;
                float th1m = th * (1.f - th);
                float num = bh2 * (delta * th * th + d0 * th1m);
                float den = delta + (d0 + d1 - 2.f * delta) * th1m;
                float y = y0 + num / den;
                float omth = 1.f - th;
                float dnum = delta * delta * (d1 * th * th + 2.f * delta * th1m + d0 * omth * omth);
                float ldv = logf(dnum) - 2.f * logf(den);
                sY[r][t] = inside ? y : xin;
                ldsum += inside ? ldv : 0.f;
            }
            sLdp[t2][r] = ldsum;
        }
        __syncthreads();

        // ================= rebuild x (+perm) and ldet, 256 threads =================
        {
            int r = tid >> 2, f0 = (tid & 3) * 4;
            if (l < NL - 1) {
                #pragma unroll
                for (int ff = 0; ff < 4; ++ff) {
                    int f = f0 + ff;
                    int g = sPerm[l * FDIM + f];
                    float v = ((g & 1) == (l & 1)) ? sY[r][g >> 1] : sX[cur][r][g];
                    sX[cur ^ 1][r][f] = v;
                }
                if (f0 == 0)
                    sLdet[r] += sLdp[0][r] + sLdp[1][r] + sLdp[2][r] + sLdp[3][r];
            } else {
                float4 o;
                float ov[4];
                #pragma unroll
                for (int ff = 0; ff < 4; ++ff) {
                    int f = f0 + ff;
                    float v = ((f & 1) == (l & 1)) ? sY[r][f >> 1] : sX[cur][r][f];
                    ov[ff] = fminf(fmaxf(v, -1.f), 1.f);
                }
                o.x = ov[0]; o.y = ov[1]; o.z = ov[2]; o.w = ov[3];
                *(float4*)&out[(size_t)(rbase + r) * FDIM + f0] = o;
                if (f0 == 0)
                    out[(size_t)BATCH * FDIM + rbase + r] =
                        sLdet[r] + sLdp[0][r] + sLdp[1][r] + sLdp[2][r] + sLdp[3][r];
            }
        }
        cur ^= 1;
    }
}

extern "C" void kernel_launch(void* const* d_in, const int* in_sizes, int n_in,
                              void* d_out, int out_size, void* d_ws, size_t ws_size,
                              hipStream_t stream) {
    (void)in_sizes; (void)n_in; (void)out_size; (void)ws_size;
    const float* inputs  = (const float*)d_in[0];
    const float* context = (const float*)d_in[1];
    const float* W1 = (const float*)d_in[2];
    const float* b1 = (const float*)d_in[3];
    const float* W2 = (const float*)d_in[4];
    const float* b2 = (const float*)d_in[5];
    const float* W3 = (const float*)d_in[6];
    const float* b3 = (const float*)d_in[7];
    const int*   perms = (const int*)d_in[8];
    float* out = (float*)d_out;

    f16* W1h = (f16*)d_ws;
    f16* W1l = W1h + (size_t)NL * HDIM * K1;
    f16* W2h = W1l + (size_t)NL * HDIM * K1;
    f16* W2l = W2h + (size_t)NL * HDIM * HDIM;
    f16* W3h = W2l + (size_t)NL * HDIM * HDIM;
    f16* W3l = W3h + (size_t)NL * N3P * HDIM;
    f16* ctxh = W3l + (size_t)NL * N3P * HDIM;
    f16* ctxl = ctxh + (size_t)BATCH * CDIM;

    int n1 = NL * HDIM * K1;
    conv_w1_kernel<<<(n1 + 255) / 256, 256, 0, stream>>>(W1, W1h, W1l);
    int n2 = NL * HDIM * HDIM;
    conv_w2_kernel<<<(n2 + 255) / 256, 256, 0, stream>>>(W2, W2h, W2l);
    int n3 = NL * N3P * HDIM;
    conv_w3_kernel<<<(n3 + 255) / 256, 256, 0, stream>>>(W3, W3h, W3l);
    int nc = BATCH * CDIM / 4;
    conv_ctx_kernel<<<(nc + 255) / 256, 256, 0, stream>>>(context, ctxh, ctxl);

    flow_kernel<<<BATCH / 64, 256, 0, stream>>>(
        inputs, ctxh, ctxl, W1h, W1l, W2h, W2l, W3h, W3l,
        b1, b2, b3, perms, out);
}